// Round 6
// baseline (471.674 us; speedup 1.0000x reference)
//
#include <hip/hip_runtime.h>
#include <stdint.h>

typedef __bf16 bf16_t;
typedef bf16_t bf16x8 __attribute__((ext_vector_type(8)));
typedef bf16_t bf16x4 __attribute__((ext_vector_type(4)));
typedef bf16_t bf16x2 __attribute__((ext_vector_type(2)));
typedef float  f32x4  __attribute__((ext_vector_type(4)));

#define IN_C 512
#define HID  256
#define OUTC 128

__device__ inline bf16x8 cvt8(float4 a, float4 b) {
  bf16x8 o;
  o[0] = (bf16_t)a.x; o[1] = (bf16_t)a.y; o[2] = (bf16_t)a.z; o[3] = (bf16_t)a.w;
  o[4] = (bf16_t)b.x; o[5] = (bf16_t)b.y; o[6] = (bf16_t)b.z; o[7] = (bf16_t)b.w;
  return o;
}

// ---------------- edge format detection ----------------
__global__ void k_detect(const void* __restrict__ ei, int* __restrict__ flag, int n_nodes) {
  if (blockIdx.x == 0 && threadIdx.x == 0) {
    const long long* p = (const long long*)ei;
    int ok = 1;
    for (int i = 0; i < 64; ++i) {
      long long v = p[i];
      if (v < 0 || v >= n_nodes) ok = 0;
    }
    *flag = ok;  // 1 => int64 layout, 0 => int32 layout
  }
}

__global__ void k_hist(const void* __restrict__ ei, const int* __restrict__ flag,
                       int* __restrict__ cnt, int E) {
  int e = blockIdx.x * blockDim.x + threadIdx.x;
  if (e >= E) return;
  int d;
  if (*flag) d = (int)((const long long*)ei)[(size_t)E + e];
  else       d = ((const int*)ei)[E + e];
  atomicAdd(&cnt[d], 1);
}

// ---------------- CSR build: scan (dinv fused) + fill ----------------
__global__ void k_scan1(const int* __restrict__ cnt, int* __restrict__ ex,
                        int* __restrict__ part, float* __restrict__ dinv, int n) {
  __shared__ int sh[256];
  int i = blockIdx.x * 256 + threadIdx.x;
  int v = (i < n) ? cnt[i] : 0;
  if (i < n) dinv[i] = rsqrtf((float)v + 1.0f);  // +1 self-loop
  sh[threadIdx.x] = v;
  __syncthreads();
  int val = v;
  for (int off = 1; off < 256; off <<= 1) {
    int t = (threadIdx.x >= off) ? sh[threadIdx.x - off] : 0;
    __syncthreads();
    val += t;
    sh[threadIdx.x] = val;
    __syncthreads();
  }
  if (i < n) ex[i] = val - v;
  if (threadIdx.x == 255) part[blockIdx.x] = val;
}

__global__ void k_scan2(int* __restrict__ part, int nb) {
  __shared__ int sh[256];
  int v = (threadIdx.x < nb) ? part[threadIdx.x] : 0;
  sh[threadIdx.x] = v;
  __syncthreads();
  int val = v;
  for (int off = 1; off < 256; off <<= 1) {
    int t = (threadIdx.x >= off) ? sh[threadIdx.x - off] : 0;
    __syncthreads();
    val += t;
    sh[threadIdx.x] = val;
    __syncthreads();
  }
  if (threadIdx.x < nb) part[threadIdx.x] = val - v;
}

__global__ void k_scan3(int* __restrict__ rs, const int* __restrict__ part,
                        int* __restrict__ cur, int n, int Etot) {
  int i = blockIdx.x * 256 + threadIdx.x;
  if (i < n) {
    int r = rs[i] + part[blockIdx.x];
    rs[i] = r;
    cur[i] = r;
  }
  if (i == 0) rs[n] = Etot;
}

// CSR fill; entry = {src, dinv[src]} packed in one 8B store
__global__ void k_fill(const void* __restrict__ ei, const int* __restrict__ flag,
                       int* __restrict__ cur, int2* __restrict__ csrw,
                       const float* __restrict__ dinv, int E) {
  int e = blockIdx.x * blockDim.x + threadIdx.x;
  if (e >= E) return;
  int s, d;
  if (*flag) {
    const long long* p = (const long long*)ei;
    s = (int)p[e];
    d = (int)p[(size_t)E + e];
  } else {
    const int* p = (const int*)ei;
    s = p[e];
    d = p[E + e];
  }
  int pos = atomicAdd(&cur[d], 1);
  int2 v;
  v.x = s;
  v.y = __float_as_int(dinv[s]);
  csrw[pos] = v;
}

// ---------------- weight prep ----------------
// W1 [512,256] -> W1t [256,512] bf16 ; W2 [256,128] -> W2t [128,256] bf16
__global__ void k_transw(const float* __restrict__ W1, const float* __restrict__ W2,
                         bf16_t* __restrict__ W1t, bf16_t* __restrict__ W2t) {
  int t = blockIdx.x * blockDim.x + threadIdx.x;
  if (t < IN_C * HID) {
    int k = t >> 8, col = t & 255;
    W1t[(size_t)col * IN_C + k] = (bf16_t)W1[t];
  } else {
    int u = t - IN_C * HID;
    if (u < HID * OUTC) {
      int k = u >> 7, col = u & 127;
      W2t[(size_t)col * HID + k] = (bf16_t)W2[u];
    }
  }
}

// ---------------- GEMM1: H1b[mpad,256] = bf16( x[fp32][n,512] @ W1 ) ----------
// BM=32 per block; 4 waves split N (64 cols each). No LDS, no barriers.
// Grid ~1563 blocks -> ~6 blocks/CU; acc only 32 VGPR/wave.
__global__ __launch_bounds__(256, 4) void k_gemm1(const float* __restrict__ x,
                                                  const bf16_t* __restrict__ W1t,
                                                  bf16_t* __restrict__ C, int n) {
  const int bm = blockIdx.x;
  const int wv = threadIdx.x >> 6, lane = threadIdx.x & 63;
  const int quad = lane >> 4, l16 = lane & 15;
  const int r0 = bm * 32 + l16;
  const int r1 = r0 + 16;
  const bool v0 = r0 < n, v1 = r1 < n;
  const float* p0 = x + (size_t)r0 * IN_C + quad * 8;
  const float* p1 = x + (size_t)r1 * IN_C + quad * 8;
  const bf16_t* pb = W1t + (size_t)(wv * 64 + l16) * IN_C + quad * 8;

  f32x4 acc[2][4];
#pragma unroll
  for (int i = 0; i < 2; ++i)
#pragma unroll
    for (int j = 0; j < 4; ++j)
#pragma unroll
      for (int r = 0; r < 4; ++r) acc[i][j][r] = 0.0f;

  float4 A0a, A0b, A1a, A1b;
  A0a = v0 ? *(const float4*)(p0)     : float4{0, 0, 0, 0};
  A0b = v0 ? *(const float4*)(p0 + 4) : float4{0, 0, 0, 0};
  A1a = v1 ? *(const float4*)(p1)     : float4{0, 0, 0, 0};
  A1b = v1 ? *(const float4*)(p1 + 4) : float4{0, 0, 0, 0};

#pragma unroll
  for (int kb = 0; kb < 16; ++kb) {  // BK = 32
    float4 N0a, N0b, N1a, N1b;
    if (kb < 15) {
      int o = (kb + 1) * 32;
      N0a = v0 ? *(const float4*)(p0 + o)     : float4{0, 0, 0, 0};
      N0b = v0 ? *(const float4*)(p0 + o + 4) : float4{0, 0, 0, 0};
      N1a = v1 ? *(const float4*)(p1 + o)     : float4{0, 0, 0, 0};
      N1b = v1 ? *(const float4*)(p1 + o + 4) : float4{0, 0, 0, 0};
    }
    bf16x8 af0 = cvt8(A0a, A0b);
    bf16x8 af1 = cvt8(A1a, A1b);
#pragma unroll
    for (int j = 0; j < 4; ++j) {
      bf16x8 bf = *(const bf16x8*)(pb + (size_t)j * 16 * IN_C + kb * 32);
      acc[0][j] = __builtin_amdgcn_mfma_f32_16x16x32_bf16(af0, bf, acc[0][j], 0, 0, 0);
      acc[1][j] = __builtin_amdgcn_mfma_f32_16x16x32_bf16(af1, bf, acc[1][j], 0, 0, 0);
    }
    A0a = N0a; A0b = N0b; A1a = N1a; A1b = N1b;
  }

#pragma unroll
  for (int i = 0; i < 2; ++i) {
#pragma unroll
    for (int j = 0; j < 4; ++j) {
      int col = wv * 64 + j * 16 + l16;
      int rw0 = bm * 32 + i * 16 + quad * 4;
#pragma unroll
      for (int r = 0; r < 4; ++r)
        C[(size_t)(rw0 + r) * HID + col] = (bf16_t)acc[i][j][r];
    }
  }
}

// ---------------- GEMM2: H2b[mpad,128] = bf16( R1b[mpad,256] @ W2 ) ----------
// BM=32 per block; 4 waves split N (32 cols each). No LDS, no barriers.
__global__ __launch_bounds__(256, 4) void k_gemm2(const bf16_t* __restrict__ A,
                                                  const bf16_t* __restrict__ W2t,
                                                  bf16_t* __restrict__ C) {
  const int bm = blockIdx.x;
  const int wv = threadIdx.x >> 6, lane = threadIdx.x & 63;
  const int quad = lane >> 4, l16 = lane & 15;
  const int r0 = bm * 32 + l16;
  const int r1 = r0 + 16;
  const bf16_t* p0 = A + (size_t)r0 * HID + quad * 8;
  const bf16_t* p1 = A + (size_t)r1 * HID + quad * 8;
  const bf16_t* pb = W2t + (size_t)(wv * 32 + l16) * HID + quad * 8;

  f32x4 acc[2][2];
#pragma unroll
  for (int i = 0; i < 2; ++i)
#pragma unroll
    for (int j = 0; j < 2; ++j)
#pragma unroll
      for (int r = 0; r < 4; ++r) acc[i][j][r] = 0.0f;

  bf16x8 af0 = *(const bf16x8*)(p0);
  bf16x8 af1 = *(const bf16x8*)(p1);

#pragma unroll
  for (int kb = 0; kb < 8; ++kb) {  // BK = 32
    bf16x8 n0, n1;
    if (kb < 7) {
      n0 = *(const bf16x8*)(p0 + (kb + 1) * 32);
      n1 = *(const bf16x8*)(p1 + (kb + 1) * 32);
    }
#pragma unroll
    for (int j = 0; j < 2; ++j) {
      bf16x8 bf = *(const bf16x8*)(pb + (size_t)j * 16 * HID + kb * 32);
      acc[0][j] = __builtin_amdgcn_mfma_f32_16x16x32_bf16(af0, bf, acc[0][j], 0, 0, 0);
      acc[1][j] = __builtin_amdgcn_mfma_f32_16x16x32_bf16(af1, bf, acc[1][j], 0, 0, 0);
    }
    af0 = n0; af1 = n1;
  }

#pragma unroll
  for (int i = 0; i < 2; ++i) {
#pragma unroll
    for (int j = 0; j < 2; ++j) {
      int col = wv * 32 + j * 16 + l16;
      int rw0 = bm * 32 + i * 16 + quad * 4;
#pragma unroll
      for (int r = 0; r < 4; ++r)
        C[(size_t)(rw0 + r) * OUTC + col] = (bf16_t)acc[i][j][r];
    }
  }
}

// ---------------- layer-1 aggregation (bf16 gather, 8 in flight) ----------
__global__ void k_agg_l1(const bf16_t* __restrict__ H, const int* __restrict__ rs,
                         const int2* __restrict__ csrw, const float* __restrict__ dinv,
                         const float* __restrict__ b1, bf16_t* __restrict__ R,
                         int n, int mpad) {
  int d = blockIdx.x * 4 + (threadIdx.x >> 6);
  if (d >= mpad) return;
  int lane = threadIdx.x & 63;
  if (d >= n) {
    bf16x4 z;
    z[0] = (bf16_t)0.0f; z[1] = (bf16_t)0.0f; z[2] = (bf16_t)0.0f; z[3] = (bf16_t)0.0f;
    *(bf16x4*)(R + (size_t)d * HID + lane * 4) = z;
    return;
  }
  int e0 = rs[d], e1 = rs[d + 1];
  float acc[4][4];
  for (int k = 0; k < 4; ++k)
    for (int c = 0; c < 4; ++c) acc[k][c] = 0.f;
  int e = e0;
  for (; e + 8 <= e1; e += 8) {
    int2 cw[8];
    bf16x4 h[8];
#pragma unroll
    for (int u = 0; u < 8; ++u) cw[u] = csrw[e + u];
#pragma unroll
    for (int u = 0; u < 8; ++u)
      h[u] = *(const bf16x4*)(H + (size_t)cw[u].x * HID + lane * 4);
#pragma unroll
    for (int u = 0; u < 8; ++u) {
      float w = __int_as_float(cw[u].y);
#pragma unroll
      for (int c = 0; c < 4; ++c) acc[u & 3][c] += w * (float)h[u][c];
    }
  }
  for (; e < e1; ++e) {
    int2 cw = csrw[e];
    float w = __int_as_float(cw.y);
    bf16x4 hx = *(const bf16x4*)(H + (size_t)cw.x * HID + lane * 4);
#pragma unroll
    for (int c = 0; c < 4; ++c) acc[0][c] += w * (float)hx[c];
  }
  float dd = dinv[d];
  float dv2 = dd * dd;
  bf16x4 hs = *(const bf16x4*)(H + (size_t)d * HID + lane * 4);
  float4 bb = ((const float4*)b1)[lane];
  float a0 = (acc[0][0] + acc[1][0]) + (acc[2][0] + acc[3][0]);
  float a1 = (acc[0][1] + acc[1][1]) + (acc[2][1] + acc[3][1]);
  float a2 = (acc[0][2] + acc[1][2]) + (acc[2][2] + acc[3][2]);
  float a3 = (acc[0][3] + acc[1][3]) + (acc[2][3] + acc[3][3]);
  float v0 = fmaxf(a0 * dd + dv2 * (float)hs[0] + bb.x, 0.f);
  float v1 = fmaxf(a1 * dd + dv2 * (float)hs[1] + bb.y, 0.f);
  float v2 = fmaxf(a2 * dd + dv2 * (float)hs[2] + bb.z, 0.f);
  float v3 = fmaxf(a3 * dd + dv2 * (float)hs[3] + bb.w, 0.f);
  bf16x4 o;
  o[0] = (bf16_t)v0; o[1] = (bf16_t)v1; o[2] = (bf16_t)v2; o[3] = (bf16_t)v3;
  *(bf16x4*)(R + (size_t)d * HID + lane * 4) = o;
}

// ---------------- layer-2 aggregation (bf16 gather, 8 in flight) ----------
__global__ void k_agg_l2(const bf16_t* __restrict__ H, const int* __restrict__ rs,
                         const int2* __restrict__ csrw, const float* __restrict__ dinv,
                         const float* __restrict__ b2, float* __restrict__ out, int n) {
  int d = blockIdx.x * 4 + (threadIdx.x >> 6);
  if (d >= n) return;
  int lane = threadIdx.x & 63;
  int e0 = rs[d], e1 = rs[d + 1];
  float acc[4][2];
  for (int k = 0; k < 4; ++k) { acc[k][0] = 0.f; acc[k][1] = 0.f; }
  int e = e0;
  for (; e + 8 <= e1; e += 8) {
    int2 cw[8];
    bf16x2 h[8];
#pragma unroll
    for (int u = 0; u < 8; ++u) cw[u] = csrw[e + u];
#pragma unroll
    for (int u = 0; u < 8; ++u)
      h[u] = *(const bf16x2*)(H + (size_t)cw[u].x * OUTC + lane * 2);
#pragma unroll
    for (int u = 0; u < 8; ++u) {
      float w = __int_as_float(cw[u].y);
      acc[u & 3][0] += w * (float)h[u][0];
      acc[u & 3][1] += w * (float)h[u][1];
    }
  }
  for (; e < e1; ++e) {
    int2 cw = csrw[e];
    float w = __int_as_float(cw.y);
    bf16x2 hx = *(const bf16x2*)(H + (size_t)cw.x * OUTC + lane * 2);
    acc[0][0] += w * (float)hx[0];
    acc[0][1] += w * (float)hx[1];
  }
  float a0 = (acc[0][0] + acc[1][0]) + (acc[2][0] + acc[3][0]);
  float a1 = (acc[0][1] + acc[1][1]) + (acc[2][1] + acc[3][1]);
  float dd = dinv[d];
  float dv2 = dd * dd;
  bf16x2 hs = *(const bf16x2*)(H + (size_t)d * OUTC + lane * 2);
  float2 bb = ((const float2*)b2)[lane];
  float2 o;
  o.x = a0 * dd + dv2 * (float)hs[0] + bb.x;
  o.y = a1 * dd + dv2 * (float)hs[1] + bb.y;
  ((float2*)(out + (size_t)d * OUTC))[lane] = o;
}

// ---------------- launch ----------------
extern "C" void kernel_launch(void* const* d_in, const int* in_sizes, int n_in,
                              void* d_out, int out_size, void* d_ws, size_t ws_size,
                              hipStream_t stream) {
  const float* x  = (const float*)d_in[0];
  const void*  ei = d_in[1];
  const float* W1 = (const float*)d_in[2];
  const float* b1 = (const float*)d_in[3];
  const float* W2 = (const float*)d_in[4];
  const float* b2 = (const float*)d_in[5];

  const int n = in_sizes[0] / IN_C;    // 50000
  const int E = in_sizes[1] / 2;       // 800000
  const int mpad = (n + 31) & ~31;     // 50016 (multiple of 32)

  char* w = (char*)d_ws;
  size_t off = 0;
  auto alloc = [&](size_t bytes) -> void* {
    void* p = w + off;
    off = (off + bytes + 255) & ~(size_t)255;
    return p;
  };

  int*    flag = (int*)alloc(4);
  int*    cnt  = (int*)alloc((size_t)n * 4);
  float*  dinv = (float*)alloc((size_t)n * 4);
  int*    rs   = (int*)alloc((size_t)(n + 1) * 4);
  int*    cur  = (int*)alloc((size_t)n * 4);
  int*    part = (int*)alloc(1024);
  int2*   csrw = (int2*)alloc((size_t)E * 8);
  bf16_t* W1t  = (bf16_t*)alloc((size_t)HID * IN_C * 2);
  bf16_t* W2t  = (bf16_t*)alloc((size_t)OUTC * HID * 2);
  bf16_t* H1b  = (bf16_t*)alloc((size_t)mpad * HID * 2);
  bf16_t* R1b  = (bf16_t*)alloc((size_t)mpad * HID * 2);
  bf16_t* H2b  = (bf16_t*)alloc((size_t)mpad * OUTC * 2);
  (void)ws_size; (void)n_in; (void)out_size;

  const int nb = (n + 255) / 256;

  hipMemsetAsync(cnt, 0, (size_t)n * 4, stream);
  k_detect<<<1, 64, 0, stream>>>(ei, flag, n);
  k_hist<<<(E + 255) / 256, 256, 0, stream>>>(ei, flag, cnt, E);
  k_scan1<<<nb, 256, 0, stream>>>(cnt, rs, part, dinv, n);
  k_scan2<<<1, 256, 0, stream>>>(part, nb);
  k_scan3<<<nb, 256, 0, stream>>>(rs, part, cur, n, E);
  k_fill<<<(E + 255) / 256, 256, 0, stream>>>(ei, flag, cur, csrw, dinv, E);
  k_transw<<<(IN_C * HID + HID * OUTC + 255) / 256, 256, 0, stream>>>(W1, W2, W1t, W2t);

  k_gemm1<<<mpad / 32, 256, 0, stream>>>(x, W1t, H1b, n);
  k_agg_l1<<<(mpad + 3) / 4, 256, 0, stream>>>(H1b, rs, csrw, dinv, b1, R1b, n, mpad);
  k_gemm2<<<mpad / 32, 256, 0, stream>>>(R1b, W2t, H2b);
  k_agg_l2<<<(n + 3) / 4, 256, 0, stream>>>(H2b, rs, csrw, dinv, b2, (float*)d_out, n);
}

// Round 7
// 398.318 us; speedup vs baseline: 1.1842x; 1.1842x over previous
//
#include <hip/hip_runtime.h>
#include <stdint.h>

typedef __bf16 bf16_t;
typedef bf16_t bf16x8 __attribute__((ext_vector_type(8)));
typedef bf16_t bf16x4 __attribute__((ext_vector_type(4)));
typedef bf16_t bf16x2 __attribute__((ext_vector_type(2)));
typedef float  f32x4  __attribute__((ext_vector_type(4)));

#define IN_C 512
#define HID  256
#define OUTC 128

// ---------------- fused prep: convx + transposes + cnt zero + format detect ----
// thread ranges: [0, mpad*64)        : x fp32 -> Xb bf16 (8 elems/thread, pad rows 0)
//                [+0, +131072)       : W1 [512,256] -> W1t [256,512] bf16
//                [+0, +32768)        : W2 [256,128] -> W2t [128,256] bf16
//                [+0, +n)            : cnt[u] = 0
//                [+n, +n+1)          : edge dtype detect -> flag
__global__ void k_prep(const float* __restrict__ x, const float* __restrict__ W1,
                       const float* __restrict__ W2, const void* __restrict__ ei,
                       int* __restrict__ flag, int* __restrict__ cnt,
                       bf16_t* __restrict__ Xb, bf16_t* __restrict__ W1t,
                       bf16_t* __restrict__ W2t, int n, int mpad) {
  int t = blockIdx.x * blockDim.x + threadIdx.x;
  const int NC = mpad * 64;
  if (t < NC) {
    int r = t >> 6, c8 = t & 63;
    bf16x8 o;
    if (r < n) {
      const float4* px = (const float4*)(x + (size_t)r * IN_C);
      float4 a = px[c8 * 2];
      float4 b = px[c8 * 2 + 1];
      o[0] = (bf16_t)a.x; o[1] = (bf16_t)a.y; o[2] = (bf16_t)a.z; o[3] = (bf16_t)a.w;
      o[4] = (bf16_t)b.x; o[5] = (bf16_t)b.y; o[6] = (bf16_t)b.z; o[7] = (bf16_t)b.w;
    } else {
      for (int i = 0; i < 8; ++i) o[i] = (bf16_t)0.0f;
    }
    *(bf16x8*)(Xb + (size_t)r * IN_C + c8 * 8) = o;
    return;
  }
  int u = t - NC;
  if (u < IN_C * HID) {
    W1t[(size_t)(u & 255) * IN_C + (u >> 8)] = (bf16_t)W1[u];
    return;
  }
  u -= IN_C * HID;
  if (u < HID * OUTC) {
    W2t[(size_t)(u & 127) * HID + (u >> 7)] = (bf16_t)W2[u];
    return;
  }
  u -= HID * OUTC;
  if (u < n) {
    cnt[u] = 0;
    return;
  }
  if (u == n) {
    const long long* p = (const long long*)ei;
    int ok = 1;
    for (int i = 0; i < 64; ++i) {
      long long v = p[i];
      if (v < 0 || v >= n) ok = 0;
    }
    *flag = ok;  // 1 => int64 layout, 0 => int32 layout
  }
}

__global__ void k_hist(const void* __restrict__ ei, const int* __restrict__ flag,
                       int* __restrict__ cnt, int E) {
  int e = blockIdx.x * blockDim.x + threadIdx.x;
  if (e >= E) return;
  int d;
  if (*flag) d = (int)((const long long*)ei)[(size_t)E + e];
  else       d = ((const int*)ei)[E + e];
  atomicAdd(&cnt[d], 1);
}

// ---------------- CSR build: scan (dinv fused) + fill ----------------
__global__ void k_scan1(const int* __restrict__ cnt, int* __restrict__ ex,
                        int* __restrict__ part, float* __restrict__ dinv, int n) {
  __shared__ int sh[256];
  int i = blockIdx.x * 256 + threadIdx.x;
  int v = (i < n) ? cnt[i] : 0;
  if (i < n) dinv[i] = rsqrtf((float)v + 1.0f);  // +1 self-loop
  sh[threadIdx.x] = v;
  __syncthreads();
  int val = v;
  for (int off = 1; off < 256; off <<= 1) {
    int t = (threadIdx.x >= off) ? sh[threadIdx.x - off] : 0;
    __syncthreads();
    val += t;
    sh[threadIdx.x] = val;
    __syncthreads();
  }
  if (i < n) ex[i] = val - v;
  if (threadIdx.x == 255) part[blockIdx.x] = val;
}

__global__ void k_scan2(int* __restrict__ part, int nb) {
  __shared__ int sh[256];
  int v = (threadIdx.x < nb) ? part[threadIdx.x] : 0;
  sh[threadIdx.x] = v;
  __syncthreads();
  int val = v;
  for (int off = 1; off < 256; off <<= 1) {
    int t = (threadIdx.x >= off) ? sh[threadIdx.x - off] : 0;
    __syncthreads();
    val += t;
    sh[threadIdx.x] = val;
    __syncthreads();
  }
  if (threadIdx.x < nb) part[threadIdx.x] = val - v;
}

__global__ void k_scan3(int* __restrict__ rs, const int* __restrict__ part,
                        int* __restrict__ cur, int n, int Etot) {
  int i = blockIdx.x * 256 + threadIdx.x;
  if (i < n) {
    int r = rs[i] + part[blockIdx.x];
    rs[i] = r;
    cur[i] = r;
  }
  if (i == 0) rs[n] = Etot;
}

// CSR fill; entry = {src, dinv[src]} packed in one 8B store
__global__ void k_fill(const void* __restrict__ ei, const int* __restrict__ flag,
                       int* __restrict__ cur, int2* __restrict__ csrw,
                       const float* __restrict__ dinv, int E) {
  int e = blockIdx.x * blockDim.x + threadIdx.x;
  if (e >= E) return;
  int s, d;
  if (*flag) {
    const long long* p = (const long long*)ei;
    s = (int)p[e];
    d = (int)p[(size_t)E + e];
  } else {
    const int* p = (const int*)ei;
    s = p[e];
    d = p[E + e];
  }
  int pos = atomicAdd(&cur[d], 1);
  int2 v;
  v.x = s;
  v.y = __float_as_int(dinv[s]);
  csrw[pos] = v;
}

// ---------------- bf16 MFMA GEMM: C[M,N] = A[M,K] * Bt[N,K]^T, bf16 output ----
// R2-proven structure: BM=BN=128, BK=32, 256 threads (4 waves, 2x2 of 64x64).
__global__ __launch_bounds__(256, 2) void k_gemm(const bf16_t* __restrict__ A,
                                                 const bf16_t* __restrict__ Bt,
                                                 bf16_t* __restrict__ C,
                                                 int Kdim, int Ncols) {
  __shared__ bf16_t As[128 * 40];
  __shared__ bf16_t Bs[128 * 40];
  const int bm = blockIdx.x, bn = blockIdx.y;
  const int tid = threadIdx.x;
  const int wave = tid >> 6, lane = tid & 63;
  const int wm = (wave >> 1) * 64, wn = (wave & 1) * 64;
  const int quad = lane >> 4, l16 = lane & 15;
  const int seg = tid & 3;

  f32x4 acc[4][4];
  for (int i = 0; i < 4; ++i)
    for (int j = 0; j < 4; ++j)
      for (int r = 0; r < 4; ++r) acc[i][j][r] = 0.0f;

  for (int kk = 0; kk < Kdim; kk += 32) {
#pragma unroll
    for (int s = 0; s < 2; ++s) {
      int row = s * 64 + (tid >> 2);
      bf16x8 va = *(const bf16x8*)(A + (size_t)(bm * 128 + row) * Kdim + kk + seg * 8);
      *(bf16x8*)(&As[row * 40 + seg * 8]) = va;
      bf16x8 vb = *(const bf16x8*)(Bt + (size_t)(bn * 128 + row) * Kdim + kk + seg * 8);
      *(bf16x8*)(&Bs[row * 40 + seg * 8]) = vb;
    }
    __syncthreads();
    bf16x8 af[4], bfr[4];
#pragma unroll
    for (int i = 0; i < 4; ++i)
      af[i] = *(const bf16x8*)(&As[(wm + i * 16 + l16) * 40 + quad * 8]);
#pragma unroll
    for (int j = 0; j < 4; ++j)
      bfr[j] = *(const bf16x8*)(&Bs[(wn + j * 16 + l16) * 40 + quad * 8]);
#pragma unroll
    for (int i = 0; i < 4; ++i)
#pragma unroll
      for (int j = 0; j < 4; ++j)
        acc[i][j] = __builtin_amdgcn_mfma_f32_16x16x32_bf16(af[i], bfr[j], acc[i][j], 0, 0, 0);
    __syncthreads();
  }

#pragma unroll
  for (int i = 0; i < 4; ++i) {
#pragma unroll
    for (int j = 0; j < 4; ++j) {
      int col = bn * 128 + wn + j * 16 + l16;
      int row0 = bm * 128 + wm + i * 16 + quad * 4;
#pragma unroll
      for (int r = 0; r < 4; ++r)
        C[(size_t)(row0 + r) * Ncols + col] = (bf16_t)acc[i][j][r];
    }
  }
}

// ---------------- layer-1 aggregation (bf16 gather, 8 in flight) ----------
__global__ void k_agg_l1(const bf16_t* __restrict__ H, const int* __restrict__ rs,
                         const int2* __restrict__ csrw, const float* __restrict__ dinv,
                         const float* __restrict__ b1, bf16_t* __restrict__ R,
                         int n, int mpad) {
  int d = blockIdx.x * 4 + (threadIdx.x >> 6);
  if (d >= mpad) return;
  int lane = threadIdx.x & 63;
  if (d >= n) {
    bf16x4 z;
    z[0] = (bf16_t)0.0f; z[1] = (bf16_t)0.0f; z[2] = (bf16_t)0.0f; z[3] = (bf16_t)0.0f;
    *(bf16x4*)(R + (size_t)d * HID + lane * 4) = z;
    return;
  }
  int e0 = rs[d], e1 = rs[d + 1];
  float acc[4][4];
  for (int k = 0; k < 4; ++k)
    for (int c = 0; c < 4; ++c) acc[k][c] = 0.f;
  int e = e0;
  for (; e + 8 <= e1; e += 8) {
    int2 cw[8];
    bf16x4 h[8];
#pragma unroll
    for (int u = 0; u < 8; ++u) cw[u] = csrw[e + u];
#pragma unroll
    for (int u = 0; u < 8; ++u)
      h[u] = *(const bf16x4*)(H + (size_t)cw[u].x * HID + lane * 4);
#pragma unroll
    for (int u = 0; u < 8; ++u) {
      float w = __int_as_float(cw[u].y);
#pragma unroll
      for (int c = 0; c < 4; ++c) acc[u & 3][c] += w * (float)h[u][c];
    }
  }
  for (; e < e1; ++e) {
    int2 cw = csrw[e];
    float w = __int_as_float(cw.y);
    bf16x4 hx = *(const bf16x4*)(H + (size_t)cw.x * HID + lane * 4);
#pragma unroll
    for (int c = 0; c < 4; ++c) acc[0][c] += w * (float)hx[c];
  }
  float dd = dinv[d];
  float dv2 = dd * dd;
  bf16x4 hs = *(const bf16x4*)(H + (size_t)d * HID + lane * 4);
  float4 bb = ((const float4*)b1)[lane];
  float a0 = (acc[0][0] + acc[1][0]) + (acc[2][0] + acc[3][0]);
  float a1 = (acc[0][1] + acc[1][1]) + (acc[2][1] + acc[3][1]);
  float a2 = (acc[0][2] + acc[1][2]) + (acc[2][2] + acc[3][2]);
  float a3 = (acc[0][3] + acc[1][3]) + (acc[2][3] + acc[3][3]);
  float v0 = fmaxf(a0 * dd + dv2 * (float)hs[0] + bb.x, 0.f);
  float v1 = fmaxf(a1 * dd + dv2 * (float)hs[1] + bb.y, 0.f);
  float v2 = fmaxf(a2 * dd + dv2 * (float)hs[2] + bb.z, 0.f);
  float v3 = fmaxf(a3 * dd + dv2 * (float)hs[3] + bb.w, 0.f);
  bf16x4 o;
  o[0] = (bf16_t)v0; o[1] = (bf16_t)v1; o[2] = (bf16_t)v2; o[3] = (bf16_t)v3;
  *(bf16x4*)(R + (size_t)d * HID + lane * 4) = o;
}

// ---------------- layer-2 aggregation (bf16 gather, 8 in flight) ----------
__global__ void k_agg_l2(const bf16_t* __restrict__ H, const int* __restrict__ rs,
                         const int2* __restrict__ csrw, const float* __restrict__ dinv,
                         const float* __restrict__ b2, float* __restrict__ out, int n) {
  int d = blockIdx.x * 4 + (threadIdx.x >> 6);
  if (d >= n) return;
  int lane = threadIdx.x & 63;
  int e0 = rs[d], e1 = rs[d + 1];
  float acc[4][2];
  for (int k = 0; k < 4; ++k) { acc[k][0] = 0.f; acc[k][1] = 0.f; }
  int e = e0;
  for (; e + 8 <= e1; e += 8) {
    int2 cw[8];
    bf16x2 h[8];
#pragma unroll
    for (int u = 0; u < 8; ++u) cw[u] = csrw[e + u];
#pragma unroll
    for (int u = 0; u < 8; ++u)
      h[u] = *(const bf16x2*)(H + (size_t)cw[u].x * OUTC + lane * 2);
#pragma unroll
    for (int u = 0; u < 8; ++u) {
      float w = __int_as_float(cw[u].y);
      acc[u & 3][0] += w * (float)h[u][0];
      acc[u & 3][1] += w * (float)h[u][1];
    }
  }
  for (; e < e1; ++e) {
    int2 cw = csrw[e];
    float w = __int_as_float(cw.y);
    bf16x2 hx = *(const bf16x2*)(H + (size_t)cw.x * OUTC + lane * 2);
    acc[0][0] += w * (float)hx[0];
    acc[0][1] += w * (float)hx[1];
  }
  float a0 = (acc[0][0] + acc[1][0]) + (acc[2][0] + acc[3][0]);
  float a1 = (acc[0][1] + acc[1][1]) + (acc[2][1] + acc[3][1]);
  float dd = dinv[d];
  float dv2 = dd * dd;
  bf16x2 hs = *(const bf16x2*)(H + (size_t)d * OUTC + lane * 2);
  float2 bb = ((const float2*)b2)[lane];
  float2 o;
  o.x = a0 * dd + dv2 * (float)hs[0] + bb.x;
  o.y = a1 * dd + dv2 * (float)hs[1] + bb.y;
  ((float2*)(out + (size_t)d * OUTC))[lane] = o;
}

// ---------------- launch ----------------
extern "C" void kernel_launch(void* const* d_in, const int* in_sizes, int n_in,
                              void* d_out, int out_size, void* d_ws, size_t ws_size,
                              hipStream_t stream) {
  const float* x  = (const float*)d_in[0];
  const void*  ei = d_in[1];
  const float* W1 = (const float*)d_in[2];
  const float* b1 = (const float*)d_in[3];
  const float* W2 = (const float*)d_in[4];
  const float* b2 = (const float*)d_in[5];

  const int n = in_sizes[0] / IN_C;    // 50000
  const int E = in_sizes[1] / 2;       // 800000
  const int mpad = (n + 127) & ~127;   // 50048

  char* w = (char*)d_ws;
  size_t off = 0;
  auto alloc = [&](size_t bytes) -> void* {
    void* p = w + off;
    off = (off + bytes + 255) & ~(size_t)255;
    return p;
  };

  int*    flag = (int*)alloc(4);
  int*    cnt  = (int*)alloc((size_t)n * 4);
  float*  dinv = (float*)alloc((size_t)n * 4);
  int*    rs   = (int*)alloc((size_t)(n + 1) * 4);
  int*    cur  = (int*)alloc((size_t)n * 4);
  int*    part = (int*)alloc(1024);
  int2*   csrw = (int2*)alloc((size_t)E * 8);
  bf16_t* Xb   = (bf16_t*)alloc((size_t)mpad * IN_C * 2);
  bf16_t* W1t  = (bf16_t*)alloc((size_t)HID * IN_C * 2);
  bf16_t* W2t  = (bf16_t*)alloc((size_t)OUTC * HID * 2);
  bf16_t* H1b  = (bf16_t*)alloc((size_t)mpad * HID * 2);
  bf16_t* R1b  = (bf16_t*)alloc((size_t)mpad * HID * 2);
  bf16_t* H2b  = (bf16_t*)alloc((size_t)mpad * OUTC * 2);
  (void)ws_size; (void)n_in; (void)out_size;

  const int nb = (n + 255) / 256;
  const int prepT = mpad * 64 + IN_C * HID + HID * OUTC + n + 1;

  k_prep<<<(prepT + 255) / 256, 256, 0, stream>>>(x, W1, W2, ei, flag, cnt,
                                                  Xb, W1t, W2t, n, mpad);
  k_hist<<<(E + 255) / 256, 256, 0, stream>>>(ei, flag, cnt, E);
  k_scan1<<<nb, 256, 0, stream>>>(cnt, rs, part, dinv, n);
  k_scan2<<<1, 256, 0, stream>>>(part, nb);
  k_scan3<<<nb, 256, 0, stream>>>(rs, part, cur, n, E);
  k_fill<<<(E + 255) / 256, 256, 0, stream>>>(ei, flag, cur, csrw, dinv, E);

  k_gemm<<<dim3(mpad / 128, HID / 128), 256, 0, stream>>>(Xb, W1t, H1b, IN_C, HID);
  k_agg_l1<<<(mpad + 3) / 4, 256, 0, stream>>>(H1b, rs, csrw, dinv, b1, R1b, n, mpad);
  k_gemm<<<dim3(mpad / 128, OUTC / 128), 256, 0, stream>>>(R1b, W2t, H2b, HID, OUTC);
  k_agg_l2<<<(n + 3) / 4, 256, 0, stream>>>(H2b, rs, csrw, dinv, b2, (float*)d_out, n);
}

// Round 8
// 397.020 us; speedup vs baseline: 1.1880x; 1.0033x over previous
//
#include <hip/hip_runtime.h>
#include <stdint.h>

typedef __bf16 bf16_t;
typedef bf16_t bf16x8 __attribute__((ext_vector_type(8)));
typedef bf16_t bf16x4 __attribute__((ext_vector_type(4)));
typedef bf16_t bf16x2 __attribute__((ext_vector_type(2)));
typedef float  f32x4  __attribute__((ext_vector_type(4)));

typedef __attribute__((address_space(3))) void* as3p;
typedef const __attribute__((address_space(1))) void* as1p;

#define IN_C 512
#define HID  256
#define OUTC 128

// ---------------- fused prep: convx + transposes + cnt zero + format detect ----
__global__ void k_prep(const float* __restrict__ x, const float* __restrict__ W1,
                       const float* __restrict__ W2, const void* __restrict__ ei,
                       int* __restrict__ flag, int* __restrict__ cnt,
                       bf16_t* __restrict__ Xb, bf16_t* __restrict__ W1t,
                       bf16_t* __restrict__ W2t, int n, int mpad) {
  int t = blockIdx.x * blockDim.x + threadIdx.x;
  const int NC = mpad * 64;
  if (t < NC) {
    int r = t >> 6, c8 = t & 63;
    bf16x8 o;
    if (r < n) {
      const float4* px = (const float4*)(x + (size_t)r * IN_C);
      float4 a = px[c8 * 2];
      float4 b = px[c8 * 2 + 1];
      o[0] = (bf16_t)a.x; o[1] = (bf16_t)a.y; o[2] = (bf16_t)a.z; o[3] = (bf16_t)a.w;
      o[4] = (bf16_t)b.x; o[5] = (bf16_t)b.y; o[6] = (bf16_t)b.z; o[7] = (bf16_t)b.w;
    } else {
      for (int i = 0; i < 8; ++i) o[i] = (bf16_t)0.0f;
    }
    *(bf16x8*)(Xb + (size_t)r * IN_C + c8 * 8) = o;
    return;
  }
  int u = t - NC;
  if (u < IN_C * HID) {
    W1t[(size_t)(u & 255) * IN_C + (u >> 8)] = (bf16_t)W1[u];
    return;
  }
  u -= IN_C * HID;
  if (u < HID * OUTC) {
    W2t[(size_t)(u & 127) * HID + (u >> 7)] = (bf16_t)W2[u];
    return;
  }
  u -= HID * OUTC;
  if (u < n) {
    cnt[u] = 0;
    return;
  }
  if (u == n) {
    const long long* p = (const long long*)ei;
    int ok = 1;
    for (int i = 0; i < 64; ++i) {
      long long v = p[i];
      if (v < 0 || v >= n) ok = 0;
    }
    *flag = ok;  // 1 => int64 layout, 0 => int32 layout
  }
}

__global__ void k_hist(const void* __restrict__ ei, const int* __restrict__ flag,
                       int* __restrict__ cnt, int E) {
  int e = blockIdx.x * blockDim.x + threadIdx.x;
  if (e >= E) return;
  int d;
  if (*flag) d = (int)((const long long*)ei)[(size_t)E + e];
  else       d = ((const int*)ei)[E + e];
  atomicAdd(&cnt[d], 1);
}

// ---------------- CSR build ----------------
// scan1: per-block exclusive scan; part[b] = block total; dinv fused
__global__ void k_scan1(const int* __restrict__ cnt, int* __restrict__ ex,
                        int* __restrict__ part, float* __restrict__ dinv, int n) {
  __shared__ int sh[256];
  int i = blockIdx.x * 256 + threadIdx.x;
  int v = (i < n) ? cnt[i] : 0;
  if (i < n) dinv[i] = rsqrtf((float)v + 1.0f);  // +1 self-loop
  sh[threadIdx.x] = v;
  __syncthreads();
  int val = v;
  for (int off = 1; off < 256; off <<= 1) {
    int t = (threadIdx.x >= off) ? sh[threadIdx.x - off] : 0;
    __syncthreads();
    val += t;
    sh[threadIdx.x] = val;
    __syncthreads();
  }
  if (i < n) ex[i] = val - v;
  if (threadIdx.x == 255) part[blockIdx.x] = val;
}

// scan23: each block reduces part[0..b) itself, adds, finalizes rs/cur
__global__ void k_scan23(int* __restrict__ rs, const int* __restrict__ part,
                         int* __restrict__ cur, int n, int Etot) {
  __shared__ int sh[256];
  const int b = blockIdx.x, t = threadIdx.x;
  int p = 0;
  for (int j = t; j < b; j += 256) p += part[j];
  sh[t] = p;
  __syncthreads();
  for (int off = 128; off > 0; off >>= 1) {
    if (t < off) sh[t] += sh[t + off];
    __syncthreads();
  }
  int base = sh[0];
  int i = b * 256 + t;
  if (i < n) {
    int r = rs[i] + base;
    rs[i] = r;
    cur[i] = r;
  }
  if (i == 0) rs[n] = Etot;
}

// CSR fill; entry = {src, dinv[src]} packed in one 8B store
__global__ void k_fill(const void* __restrict__ ei, const int* __restrict__ flag,
                       int* __restrict__ cur, int2* __restrict__ csrw,
                       const float* __restrict__ dinv, int E) {
  int e = blockIdx.x * blockDim.x + threadIdx.x;
  if (e >= E) return;
  int s, d;
  if (*flag) {
    const long long* p = (const long long*)ei;
    s = (int)p[e];
    d = (int)p[(size_t)E + e];
  } else {
    const int* p = (const int*)ei;
    s = p[e];
    d = p[E + e];
  }
  int pos = atomicAdd(&cur[d], 1);
  int2 v;
  v.x = s;
  v.y = __float_as_int(dinv[s]);
  csrw[pos] = v;
}

// ---------------- bf16 MFMA GEMM (m97 structure): C = A * Bt^T, bf16 out ------
// BM=BN=128, BK=32, 256 threads / 4 waves (2x2 of 64x64).
// Staging via global_load_lds width=16 into unpadded lane-ordered [128][32] tiles.
__global__ __launch_bounds__(256, 3) void k_gemm(const bf16_t* __restrict__ A,
                                                 const bf16_t* __restrict__ Bt,
                                                 bf16_t* __restrict__ C,
                                                 int Kdim, int Ncols) {
  __shared__ bf16_t As[128 * 32];
  __shared__ bf16_t Bs[128 * 32];
  const int bm = blockIdx.x, bn = blockIdx.y;
  const int tid = threadIdx.x;
  const int wave = tid >> 6, lane = tid & 63;
  const int wm = (wave >> 1) * 64, wn = (wave & 1) * 64;
  const int quad = lane >> 4, l16 = lane & 15;

  const size_t abase = (size_t)bm * 128 * Kdim;
  const size_t bbase = (size_t)bn * 128 * Kdim;

  f32x4 acc[4][4];
#pragma unroll
  for (int i = 0; i < 4; ++i)
#pragma unroll
    for (int j = 0; j < 4; ++j)
#pragma unroll
      for (int r = 0; r < 4; ++r) acc[i][j][r] = 0.0f;

  for (int kk = 0; kk < Kdim; kk += 32) {
    // stage 8KB As + 8KB Bs: 512 chunks of 16B each; chunk g: row=g>>2, col=(g&3)*8
#pragma unroll
    for (int i = 0; i < 2; ++i) {
      int g = i * 256 + tid;
      int row = g >> 2, col = (g & 3) * 8;
      const bf16_t* ga = A + abase + (size_t)row * Kdim + kk + col;
      __builtin_amdgcn_global_load_lds((as1p)ga,
                                       (as3p)(&As[(i * 256 + wave * 64) * 8]), 16, 0, 0);
      const bf16_t* gb = Bt + bbase + (size_t)row * Kdim + kk + col;
      __builtin_amdgcn_global_load_lds((as1p)gb,
                                       (as3p)(&Bs[(i * 256 + wave * 64) * 8]), 16, 0, 0);
    }
    __syncthreads();
    bf16x8 af[4], bf[4];
#pragma unroll
    for (int i = 0; i < 4; ++i)
      af[i] = *(const bf16x8*)(&As[(wm + i * 16 + l16) * 32 + quad * 8]);
#pragma unroll
    for (int j = 0; j < 4; ++j)
      bf[j] = *(const bf16x8*)(&Bs[(wn + j * 16 + l16) * 32 + quad * 8]);
#pragma unroll
    for (int i = 0; i < 4; ++i)
#pragma unroll
      for (int j = 0; j < 4; ++j)
        acc[i][j] = __builtin_amdgcn_mfma_f32_16x16x32_bf16(af[i], bf[j], acc[i][j], 0, 0, 0);
    __syncthreads();
  }

#pragma unroll
  for (int i = 0; i < 4; ++i) {
#pragma unroll
    for (int j = 0; j < 4; ++j) {
      int col = bn * 128 + wn + j * 16 + l16;
      int row0 = bm * 128 + wm + i * 16 + quad * 4;
#pragma unroll
      for (int r = 0; r < 4; ++r)
        C[(size_t)(row0 + r) * Ncols + col] = (bf16_t)acc[i][j][r];
    }
  }
}

// ---------------- layer-1 aggregation (bf16 gather, 8 in flight) ----------
__global__ void k_agg_l1(const bf16_t* __restrict__ H, const int* __restrict__ rs,
                         const int2* __restrict__ csrw, const float* __restrict__ dinv,
                         const float* __restrict__ b1, bf16_t* __restrict__ R,
                         int n, int mpad) {
  int d = blockIdx.x * 4 + (threadIdx.x >> 6);
  if (d >= mpad) return;
  int lane = threadIdx.x & 63;
  if (d >= n) {
    bf16x4 z;
    z[0] = (bf16_t)0.0f; z[1] = (bf16_t)0.0f; z[2] = (bf16_t)0.0f; z[3] = (bf16_t)0.0f;
    *(bf16x4*)(R + (size_t)d * HID + lane * 4) = z;
    return;
  }
  int e0 = rs[d], e1 = rs[d + 1];
  float acc[4][4];
  for (int k = 0; k < 4; ++k)
    for (int c = 0; c < 4; ++c) acc[k][c] = 0.f;
  int e = e0;
  for (; e + 8 <= e1; e += 8) {
    int2 cw[8];
    bf16x4 h[8];
#pragma unroll
    for (int u = 0; u < 8; ++u) cw[u] = csrw[e + u];
#pragma unroll
    for (int u = 0; u < 8; ++u)
      h[u] = *(const bf16x4*)(H + (size_t)cw[u].x * HID + lane * 4);
#pragma unroll
    for (int u = 0; u < 8; ++u) {
      float w = __int_as_float(cw[u].y);
#pragma unroll
      for (int c = 0; c < 4; ++c) acc[u & 3][c] += w * (float)h[u][c];
    }
  }
  for (; e < e1; ++e) {
    int2 cw = csrw[e];
    float w = __int_as_float(cw.y);
    bf16x4 hx = *(const bf16x4*)(H + (size_t)cw.x * HID + lane * 4);
#pragma unroll
    for (int c = 0; c < 4; ++c) acc[0][c] += w * (float)hx[c];
  }
  float dd = dinv[d];
  float dv2 = dd * dd;
  bf16x4 hs = *(const bf16x4*)(H + (size_t)d * HID + lane * 4);
  float4 bb = ((const float4*)b1)[lane];
  float a0 = (acc[0][0] + acc[1][0]) + (acc[2][0] + acc[3][0]);
  float a1 = (acc[0][1] + acc[1][1]) + (acc[2][1] + acc[3][1]);
  float a2 = (acc[0][2] + acc[1][2]) + (acc[2][2] + acc[3][2]);
  float a3 = (acc[0][3] + acc[1][3]) + (acc[2][3] + acc[3][3]);
  float v0 = fmaxf(a0 * dd + dv2 * (float)hs[0] + bb.x, 0.f);
  float v1 = fmaxf(a1 * dd + dv2 * (float)hs[1] + bb.y, 0.f);
  float v2 = fmaxf(a2 * dd + dv2 * (float)hs[2] + bb.z, 0.f);
  float v3 = fmaxf(a3 * dd + dv2 * (float)hs[3] + bb.w, 0.f);
  bf16x4 o;
  o[0] = (bf16_t)v0; o[1] = (bf16_t)v1; o[2] = (bf16_t)v2; o[3] = (bf16_t)v3;
  *(bf16x4*)(R + (size_t)d * HID + lane * 4) = o;
}

// ---------------- layer-2 aggregation (bf16 gather, 8 in flight) ----------
__global__ void k_agg_l2(const bf16_t* __restrict__ H, const int* __restrict__ rs,
                         const int2* __restrict__ csrw, const float* __restrict__ dinv,
                         const float* __restrict__ b2, float* __restrict__ out, int n) {
  int d = blockIdx.x * 4 + (threadIdx.x >> 6);
  if (d >= n) return;
  int lane = threadIdx.x & 63;
  int e0 = rs[d], e1 = rs[d + 1];
  float acc[4][2];
  for (int k = 0; k < 4; ++k) { acc[k][0] = 0.f; acc[k][1] = 0.f; }
  int e = e0;
  for (; e + 8 <= e1; e += 8) {
    int2 cw[8];
    bf16x2 h[8];
#pragma unroll
    for (int u = 0; u < 8; ++u) cw[u] = csrw[e + u];
#pragma unroll
    for (int u = 0; u < 8; ++u)
      h[u] = *(const bf16x2*)(H + (size_t)cw[u].x * OUTC + lane * 2);
#pragma unroll
    for (int u = 0; u < 8; ++u) {
      float w = __int_as_float(cw[u].y);
      acc[u & 3][0] += w * (float)h[u][0];
      acc[u & 3][1] += w * (float)h[u][1];
    }
  }
  for (; e < e1; ++e) {
    int2 cw = csrw[e];
    float w = __int_as_float(cw.y);
    bf16x2 hx = *(const bf16x2*)(H + (size_t)cw.x * OUTC + lane * 2);
    acc[0][0] += w * (float)hx[0];
    acc[0][1] += w * (float)hx[1];
  }
  float a0 = (acc[0][0] + acc[1][0]) + (acc[2][0] + acc[3][0]);
  float a1 = (acc[0][1] + acc[1][1]) + (acc[2][1] + acc[3][1]);
  float dd = dinv[d];
  float dv2 = dd * dd;
  bf16x2 hs = *(const bf16x2*)(H + (size_t)d * OUTC + lane * 2);
  float2 bb = ((const float2*)b2)[lane];
  float2 o;
  o.x = a0 * dd + dv2 * (float)hs[0] + bb.x;
  o.y = a1 * dd + dv2 * (float)hs[1] + bb.y;
  ((float2*)(out + (size_t)d * OUTC))[lane] = o;
}

// ---------------- launch ----------------
extern "C" void kernel_launch(void* const* d_in, const int* in_sizes, int n_in,
                              void* d_out, int out_size, void* d_ws, size_t ws_size,
                              hipStream_t stream) {
  const float* x  = (const float*)d_in[0];
  const void*  ei = d_in[1];
  const float* W1 = (const float*)d_in[2];
  const float* b1 = (const float*)d_in[3];
  const float* W2 = (const float*)d_in[4];
  const float* b2 = (const float*)d_in[5];

  const int n = in_sizes[0] / IN_C;    // 50000
  const int E = in_sizes[1] / 2;       // 800000
  const int mpad = (n + 127) & ~127;   // 50048

  char* w = (char*)d_ws;
  size_t off = 0;
  auto alloc = [&](size_t bytes) -> void* {
    void* p = w + off;
    off = (off + bytes + 255) & ~(size_t)255;
    return p;
  };

  int*    flag = (int*)alloc(4);
  int*    cnt  = (int*)alloc((size_t)n * 4);
  float*  dinv = (float*)alloc((size_t)n * 4);
  int*    rs   = (int*)alloc((size_t)(n + 1) * 4);
  int*    cur  = (int*)alloc((size_t)n * 4);
  int*    part = (int*)alloc(1024);
  int2*   csrw = (int2*)alloc((size_t)E * 8);
  bf16_t* Xb   = (bf16_t*)alloc((size_t)mpad * IN_C * 2);
  bf16_t* W1t  = (bf16_t*)alloc((size_t)HID * IN_C * 2);
  bf16_t* W2t  = (bf16_t*)alloc((size_t)OUTC * HID * 2);
  bf16_t* H1b  = (bf16_t*)alloc((size_t)mpad * HID * 2);
  bf16_t* R1b  = (bf16_t*)alloc((size_t)mpad * HID * 2);
  bf16_t* H2b  = (bf16_t*)alloc((size_t)mpad * OUTC * 2);
  (void)ws_size; (void)n_in; (void)out_size;

  const int nb = (n + 255) / 256;
  const int prepT = mpad * 64 + IN_C * HID + HID * OUTC + n + 1;

  k_prep<<<(prepT + 255) / 256, 256, 0, stream>>>(x, W1, W2, ei, flag, cnt,
                                                  Xb, W1t, W2t, n, mpad);
  k_hist<<<(E + 255) / 256, 256, 0, stream>>>(ei, flag, cnt, E);
  k_scan1<<<nb, 256, 0, stream>>>(cnt, rs, part, dinv, n);
  k_scan23<<<nb, 256, 0, stream>>>(rs, part, cur, n, E);
  k_fill<<<(E + 255) / 256, 256, 0, stream>>>(ei, flag, cur, csrw, dinv, E);

  k_gemm<<<dim3(mpad / 128, HID / 128), 256, 0, stream>>>(Xb, W1t, H1b, IN_C, HID);
  k_agg_l1<<<(mpad + 3) / 4, 256, 0, stream>>>(H1b, rs, csrw, dinv, b1, R1b, n, mpad);
  k_gemm<<<dim3(mpad / 128, OUTC / 128), 256, 0, stream>>>(R1b, W2t, H2b, HID, OUTC);
  k_agg_l2<<<(n + 3) / 4, 256, 0, stream>>>(H2b, rs, csrw, dinv, b2, (float*)d_out, n);
}